// Round 10
// baseline (179.959 us; speedup 1.0000x reference)
//
#include <hip/hip_runtime.h>

#define N_NODES 100000
#define N_EDGES 1600000
#define D 64
#define NXCD 8
#define DGU (N_NODES / 2)                 // uints per packed deg row (2 nodes/uint)
// s_getreg imm: id=20 (HW_REG_XCC_ID), offset=0, size=8 -> (7<<11)|(0<<6)|20
#define GETREG_XCC_IMM 14356

typedef __attribute__((ext_vector_type(8))) short bf16x8;
typedef __attribute__((ext_vector_type(4))) float f32x4;

__device__ __forceinline__ unsigned short f2bf(float f) {
    union { float f; unsigned u; } v; v.f = f;
    unsigned r = v.u + 0x7FFFu + ((v.u >> 16) & 1u);
    return (unsigned short)(r >> 16);
}
__device__ __forceinline__ float bf2f_u(unsigned h) {   // low 16 bits -> float
    union { unsigned u; float f; } v; v.u = h << 16;
    return v.f;
}

// ---------------- fused dst histogram/rank (XCD-local atomics) + x->bf16 convert ----
#define CVT_ITEMS ((N_NODES * D) / 4)     // 1,600,000 float4 items
#define HIST_ITEMS (N_EDGES / 4)          //   400,000 int4 items
__global__ __launch_bounds__(256) void cvthist_kernel(const float* __restrict__ x,
                                                      unsigned short* __restrict__ xb,
                                                      const int* __restrict__ ei,
                                                      unsigned* __restrict__ degp32,
                                                      unsigned short* __restrict__ rank) {
    int i = blockIdx.x * blockDim.x + threadIdx.x;
    if (i < HIST_ITEMS) {
        const int xcc = __builtin_amdgcn_s_getreg(GETREG_XCC_IMM) & (NXCD - 1);
        unsigned* dp = degp32 + (size_t)xcc * DGU;
        int4 d4 = ((const int4*)(ei + N_EDGES))[i];

        const int i0 = d4.x >> 1, s0 = (d4.x & 1) << 4;
        const int i1 = d4.y >> 1, s1 = (d4.y & 1) << 4;
        const int i2 = d4.z >> 1, s2 = (d4.z & 1) << 4;
        const int i3 = d4.w >> 1, s3 = (d4.w & 1) << 4;
        unsigned o0 = __hip_atomic_fetch_add(&dp[i0], 1u << s0, __ATOMIC_RELAXED,
                                             __HIP_MEMORY_SCOPE_WORKGROUP);
        unsigned o1 = __hip_atomic_fetch_add(&dp[i1], 1u << s1, __ATOMIC_RELAXED,
                                             __HIP_MEMORY_SCOPE_WORKGROUP);
        unsigned o2 = __hip_atomic_fetch_add(&dp[i2], 1u << s2, __ATOMIC_RELAXED,
                                             __HIP_MEMORY_SCOPE_WORKGROUP);
        unsigned o3 = __hip_atomic_fetch_add(&dp[i3], 1u << s3, __ATOMIC_RELAXED,
                                             __HIP_MEMORY_SCOPE_WORKGROUP);
        const unsigned pb = (unsigned)xcc << 13;
        unsigned r0 = pb | ((o0 >> s0) & 0xFFFFu);
        unsigned r1 = pb | ((o1 >> s1) & 0xFFFFu);
        unsigned r2 = pb | ((o2 >> s2) & 0xFFFFu);
        unsigned r3 = pb | ((o3 >> s3) & 0xFFFFu);
        uint2 packed;
        packed.x = r0 | (r1 << 16);
        packed.y = r2 | (r3 << 16);
        ((uint2*)rank)[i] = packed;
    } else if (i < HIST_ITEMS + CVT_ITEMS) {
        int j = i - HIST_ITEMS;
        float4 v = ((const float4*)x)[j];
        ushort4 o;
        o.x = f2bf(v.x); o.y = f2bf(v.y); o.z = f2bf(v.z); o.w = f2bf(v.w);
        ((ushort4*)xb)[j] = o;
    }
}

// ---------------- single-kernel decoupled-lookback scan over packed node totals ----
// Outputs: offsets[n] (int, + sentinel), cdelta[p-1][n] (ushort) = sum_{p'<p} degp[p'][n]
#define SCAN_TPB 256
#define SCAN_VPT 4
#define SCAN_TILE (SCAN_TPB * SCAN_VPT)                     // 1024
#define SCAN_NBK ((N_NODES + SCAN_TILE - 1) / SCAN_TILE)    // 98
__global__ __launch_bounds__(SCAN_TPB) void scan_kernel(const unsigned* __restrict__ degp32,
                                                        int* __restrict__ offsets,
                                                        unsigned short* __restrict__ cdelta,
                                                        unsigned long long* __restrict__ state) {
    __shared__ int sums[SCAN_TPB];
    __shared__ int sPrefix;
    const int tid = threadIdx.x;
    const int b   = blockIdx.x;
    const int base = b * SCAN_TILE + tid * SCAN_VPT;

    int d[NXCD][4];
    if (base + 3 < N_NODES) {
        #pragma unroll
        for (int p = 0; p < NXCD; ++p) {
            uint2 u = *(const uint2*)(degp32 + (size_t)p * DGU + (base >> 1));
            d[p][0] = u.x & 0xFFFF; d[p][1] = u.x >> 16;
            d[p][2] = u.y & 0xFFFF; d[p][3] = u.y >> 16;
        }
    } else {
        #pragma unroll
        for (int p = 0; p < NXCD; ++p) {
            #pragma unroll
            for (int j = 0; j < 4; ++j) {
                int n = base + j;
                int v = 0;
                if (n < N_NODES) {
                    unsigned u = degp32[(size_t)p * DGU + (n >> 1)];
                    v = (u >> ((n & 1) << 4)) & 0xFFFF;
                }
                d[p][j] = v;
            }
        }
    }

    int tot[4];
    #pragma unroll
    for (int j = 0; j < 4; ++j) {
        int t = 0;
        #pragma unroll
        for (int p = 0; p < NXCD; ++p) t += d[p][j];
        tot[j] = t;
    }
    const int tsum = tot[0] + tot[1] + tot[2] + tot[3];

    sums[tid] = tsum;
    __syncthreads();
    for (int off = 1; off < SCAN_TPB; off <<= 1) {
        int t = (tid >= off) ? sums[tid - off] : 0;
        __syncthreads();
        sums[tid] += t;
        __syncthreads();
    }
    const int incl = sums[tid];
    const int excl = incl - tsum;
    const int agg  = sums[SCAN_TPB - 1];

    if (tid == 0) {
        unsigned long long pub =
            (((unsigned long long)((b == 0) ? 2u : 1u)) << 32) | (unsigned)agg;
        __hip_atomic_store(&state[b], pub, __ATOMIC_RELEASE, __HIP_MEMORY_SCOPE_AGENT);
    }

    if (b > 0) {
        if (tid < 64) {
            const int lane = tid;
            int running = 0;
            int idx = b - 1;
            while (true) {
                const int look = idx - lane;
                unsigned long long s = 0;
                if (look >= 0) {
                    do {
                        s = __hip_atomic_load(&state[look], __ATOMIC_ACQUIRE,
                                              __HIP_MEMORY_SCOPE_AGENT);
                    } while ((s >> 32) == 0);
                }
                unsigned long long bal = __ballot(look >= 0 && (s >> 32) == 2u);
                if (bal) {
                    const int fp = __ffsll((unsigned long long)bal) - 1;
                    int val = (look >= 0 && lane <= fp) ? (int)(unsigned)s : 0;
                    #pragma unroll
                    for (int o = 1; o < 64; o <<= 1) val += __shfl_xor(val, o, 64);
                    running += val;
                    break;
                } else {
                    int val = (look >= 0) ? (int)(unsigned)s : 0;
                    #pragma unroll
                    for (int o = 1; o < 64; o <<= 1) val += __shfl_xor(val, o, 64);
                    running += val;
                    idx -= 64;
                    if (idx < 0) break;
                }
            }
            if (lane == 0) {
                sPrefix = running;
                unsigned long long pub = (2ULL << 32) | (unsigned)(running + agg);
                __hip_atomic_store(&state[b], pub, __ATOMIC_RELEASE,
                                   __HIP_MEMORY_SCOPE_AGENT);
            }
        }
    } else {
        if (tid == 0) sPrefix = 0;
    }
    __syncthreads();

    int o[4];
    o[0] = sPrefix + excl;
    o[1] = o[0] + tot[0];
    o[2] = o[1] + tot[1];
    o[3] = o[2] + tot[2];

    if (base + 3 < N_NODES) {
        int4 w; w.x = o[0]; w.y = o[1]; w.z = o[2]; w.w = o[3];
        *(int4*)(offsets + base) = w;
        unsigned c0 = d[0][0], c1 = d[0][1], c2 = d[0][2], c3 = d[0][3];
        #pragma unroll
        for (int p = 1; p < NXCD; ++p) {
            uint2 w2;
            w2.x = c0 | (c1 << 16);
            w2.y = c2 | (c3 << 16);
            *(uint2*)((unsigned*)cdelta + (size_t)(p - 1) * DGU + (base >> 1)) = w2;
            c0 += d[p][0]; c1 += d[p][1]; c2 += d[p][2]; c3 += d[p][3];
        }
    } else {
        #pragma unroll
        for (int j = 0; j < 4; ++j) {
            int n = base + j;
            if (n < N_NODES) {
                offsets[n] = o[j];
                unsigned c = d[0][j];
                #pragma unroll
                for (int p = 1; p < NXCD; ++p) {
                    cdelta[(size_t)(p - 1) * N_NODES + n] = (unsigned short)c;
                    c += d[p][j];
                }
            }
        }
    }
    if (b == SCAN_NBK - 1 && tid == SCAN_TPB - 1) offsets[N_NODES] = N_EDGES;
}

// ---------------- fill CSR (non-atomic, rank+delta based) ----------------
__global__ __launch_bounds__(256) void fill_kernel(const int* __restrict__ ei,
                                                   const int* __restrict__ offsets,
                                                   const unsigned short* __restrict__ cdelta,
                                                   const unsigned short* __restrict__ rank,
                                                   int* __restrict__ csr) {
    int i = blockIdx.x * blockDim.x + threadIdx.x;
    if (i >= N_EDGES / 4) return;
    int4 s4 = ((const int4*)ei)[i];
    int4 d4 = ((const int4*)(ei + N_EDGES))[i];
    uint2 rr = ((const uint2*)rank)[i];
    const unsigned pr[4] = { rr.x & 0xFFFFu, rr.x >> 16, rr.y & 0xFFFFu, rr.y >> 16 };
    const int dst[4] = { d4.x, d4.y, d4.z, d4.w };
    const int src[4] = { s4.x, s4.y, s4.z, s4.w };
    #pragma unroll
    for (int k = 0; k < 4; ++k) {
        const int p = pr[k] >> 13;
        const int r = pr[k] & 0x1FFF;
        const int pe = p ? (p - 1) : 0;
        const unsigned short dv = cdelta[(size_t)pe * N_NODES + dst[k]];
        const int delta = p ? (int)dv : 0;
        csr[offsets[dst[k]] + delta + r] = src[k];
    }
}

// 8 clamp-masked edge-pairs: lanes<32 take edge jj, lanes>=32 take edge jj+1,
// each lane holds 2 cols as a packed bf16 pair.
#define STEP8(SI, J, N, A0, A1)                                              \
    {                                                                         \
        _Pragma("unroll")                                                     \
        for (int t_ = 0; t_ < 8; ++t_) {                                      \
            const int jj_  = (J) + 2 * t_;                                    \
            const int jlo_ = (jj_     < (N)) ? jj_     : ((N) - 1);           \
            const int jhi_ = (jj_ + 1 < (N)) ? jj_ + 1 : ((N) - 1);           \
            const int slo_ = __builtin_amdgcn_readlane((SI), jlo_);           \
            const int shi_ = __builtin_amdgcn_readlane((SI), jhi_);           \
            const int sel_ = (lane >= 32) ? shi_ : slo_;                      \
            unsigned v_ = xb32[(size_t)sel_ * 32 + lc];                       \
            const bool ok_ = (lane < 32) ? (jj_ < (N)) : (jj_ + 1 < (N));     \
            v_ = ok_ ? v_ : 0u;                                               \
            (A0) += bf2f_u(v_ & 0xFFFFu);                                     \
            (A1) += bf2f_u(v_ >> 16);                                         \
        }                                                                     \
    }

// rare tail for degree > 64
#define TAILCH(S0, DD, A0, A1)                                               \
    for (int base_ = 64; base_ < (DD); base_ += 64) {                        \
        const int n2_ = ((DD) - base_ < 64) ? ((DD) - base_) : 64;           \
        const int cl2_ = (lane < n2_) ? lane : (n2_ - 1);                    \
        const int sit_ = csr[(S0) + base_ + cl2_];                           \
        for (int j_ = 0; j_ < n2_; j_ += 16) { STEP8(sit_, j_, n2_, A0, A1) }\
    }

// ---------------- fused gather + mean + MFMA matmul + bias + ReLU ----------------
#define NPW 16
#define SBLK 512
__global__ __launch_bounds__(SBLK) void sage_kernel(const unsigned short* __restrict__ xb,
                                                    const int* __restrict__ offsets,
                                                    const int* __restrict__ csr,
                                                    const float* __restrict__ Wl,
                                                    const float* __restrict__ bl,
                                                    const float* __restrict__ Wr,
                                                    float* __restrict__ out) {
    __shared__ unsigned short sWt[D * 2 * D];      // 64 cols x 128 k, 16 KB
    __shared__ float sbl[D];
    __shared__ unsigned int sA32[(SBLK / 64) * NPW * (2 * D / 2)];  // 8 waves x 16 rows x 64 uints

    const int tid = threadIdx.x;
    for (int i = tid; i < D * D; i += SBLK) {
        int k = i >> 6, c = i & 63;
        int swz = (c & 7) << 3;                     // ushort-index xor
        sWt[(c * 128 + k) ^ swz]      = f2bf(Wl[i]);
        sWt[(c * 128 + 64 + k) ^ swz] = f2bf(Wr[i]);
    }
    if (tid < D) sbl[tid] = bl[tid];
    __syncthreads();

    const int lane = tid & 63;
    const int wib  = tid >> 6;
    const int wid  = (blockIdx.x * (SBLK / 64)) + wib;
    const int node0 = wid * NPW;
    if (node0 >= N_NODES) return;

    const unsigned int* __restrict__ xb32 = (const unsigned int*)xb;
    unsigned int* sAw = sA32 + wib * (NPW * 64);
    const int lc = lane & 31;

    // ---- stage offsets for 17 boundaries with one lane-parallel load ----
    const int offl = offsets[node0 + ((lane <= NPW) ? lane : NPW)];

    // ---- stage csr chunk 0 for all 16 nodes (16 loads in flight) ----
    int si[NPW];
    int dg[NPW];
    #pragma unroll
    for (int r = 0; r < NPW; ++r) {
        const int s0 = __builtin_amdgcn_readlane(offl, r);
        const int s1 = __builtin_amdgcn_readlane(offl, r + 1);
        const int d  = s1 - s0;
        dg[r] = d;
        const int dm = (d > 0) ? d : 1;
        const int cl = (lane < dm) ? lane : (dm - 1);
        int addr = s0 + cl;
        addr = (addr < N_EDGES) ? addr : (N_EDGES - 1);
        si[r] = csr[addr];
    }

    // ---- gather: two nodes interleaved (16 xb loads in flight) ----
    #pragma unroll
    for (int p = 0; p < NPW / 2; ++p) {
        const int rA = 2 * p, rB = 2 * p + 1;
        const int dA = dg[rA], dB = dg[rB];
        const int nA = (dA < 64) ? dA : 64;
        const int nB = (dB < 64) ? dB : 64;

        const unsigned vselfA = xb32[(size_t)(node0 + rA) * 32 + lc];
        const unsigned vselfB = xb32[(size_t)(node0 + rB) * 32 + lc];

        float a0 = 0.0f, a1 = 0.0f, b0 = 0.0f, b1 = 0.0f;
        int jA = 0, jB = 0;
        while (jA < nA && jB < nB) {
            STEP8(si[rA], jA, nA, a0, a1)
            STEP8(si[rB], jB, nB, b0, b1)
            jA += 16; jB += 16;
        }
        while (jA < nA) { STEP8(si[rA], jA, nA, a0, a1) jA += 16; }
        while (jB < nB) { STEP8(si[rB], jB, nB, b0, b1) jB += 16; }
        if (dA > 64) {
            const int s0A = __builtin_amdgcn_readlane(offl, rA);
            TAILCH(s0A, dA, a0, a1)
        }
        if (dB > 64) {
            const int s0B = __builtin_amdgcn_readlane(offl, rB);
            TAILCH(s0B, dB, b0, b1)
        }

        a0 += __shfl_xor(a0, 32, 64);
        a1 += __shfl_xor(a1, 32, 64);
        b0 += __shfl_xor(b0, 32, 64);
        b1 += __shfl_xor(b1, 32, 64);
        const float invA = 1.0f / fmaxf((float)dA, 1.0f);
        const float invB = 1.0f / fmaxf((float)dB, 1.0f);
        const unsigned mpA = ((unsigned)f2bf(a1 * invA) << 16) | f2bf(a0 * invA);
        const unsigned mpB = ((unsigned)f2bf(b1 * invB) << 16) | f2bf(b0 * invB);
        const int swzA = (rA & 7) << 2;
        const int swzB = (rB & 7) << 2;
        if (lane < 32) {
            sAw[(rA * 64 + lc) ^ swzA] = mpA;
            sAw[(rB * 64 + lc) ^ swzB] = mpB;
        } else {
            sAw[(rA * 64 + 32 + lc) ^ swzA] = vselfA;
            sAw[(rB * 64 + 32 + lc) ^ swzB] = vselfB;
        }
    }

    // ---- MFMA phase ----
    const unsigned short* sAu = (const unsigned short*)sAw;
    const int row = lane & 15;
    const int kb  = lane >> 4;

    bf16x8 afr[4];
    #pragma unroll
    for (int kc = 0; kc < 4; ++kc) {
        int us = (row * 128 + kc * 32 + kb * 8) ^ ((row & 7) << 3);
        afr[kc] = *(const bf16x8*)(sAu + us);
    }

    #pragma unroll
    for (int ct = 0; ct < 4; ++ct) {
        const int col = ct * 16 + row;
        f32x4 acc = {0.0f, 0.0f, 0.0f, 0.0f};
        #pragma unroll
        for (int kc = 0; kc < 4; ++kc) {
            int us = (col * 128 + kc * 32 + kb * 8) ^ ((col & 7) << 3);
            bf16x8 bfr = *(const bf16x8*)(sWt + us);
            acc = __builtin_amdgcn_mfma_f32_16x16x32_bf16(afr[kc], bfr, acc, 0, 0, 0);
        }
        const float bias = sbl[col];
        const int crow0 = (lane >> 4) * 4;
        #pragma unroll
        for (int i = 0; i < 4; ++i) {
            out[(node0 + crow0 + i) * D + col] = fmaxf(acc[i] + bias, 0.0f);
        }
    }
}

// ---------------- launch ----------------
extern "C" void kernel_launch(void* const* d_in, const int* in_sizes, int n_in,
                              void* d_out, int out_size, void* d_ws, size_t ws_size,
                              hipStream_t stream) {
    const float* x  = (const float*)d_in[0];
    const int*   ei = (const int*)d_in[1];    // [2, N_EDGES] flat: src then dst
    const float* Wl = (const float*)d_in[2];
    const float* bl = (const float*)d_in[3];
    const float* Wr = (const float*)d_in[4];
    float* out = (float*)d_out;

    // workspace layout (~25.8 MB), 16B-aligned segments
    unsigned* degp32 = (unsigned*)d_ws;                                // 8 * DGU uints (1.6 MB)
    unsigned long long* state = (unsigned long long*)(degp32 + NXCD * DGU);  // 1 KB
    int* offsets = (int*)((char*)state + 1024);                        // N_NODES + 8 ints (0.4 MB)
    unsigned short* cdelta = (unsigned short*)(offsets + N_NODES + 8); // 7 * N_NODES ushorts (1.4 MB)
    int* csr = (int*)(cdelta + (NXCD - 1) * N_NODES);                  // N_EDGES (6.4 MB)
    unsigned short* rank = (unsigned short*)(csr + N_EDGES);           // N_EDGES (3.2 MB)
    unsigned short* xb   = rank + N_EDGES;                             // N_NODES * D (12.8 MB)

    // zero packed deg + scan state flags in one memset
    hipMemsetAsync(degp32, 0, (size_t)NXCD * DGU * sizeof(unsigned) + 1024, stream);

    {
        const int items = HIST_ITEMS + CVT_ITEMS;                      // 2,000,000
        cvthist_kernel<<<(items + 255) / 256, 256, 0, stream>>>(x, xb, ei, degp32, rank);
    }
    scan_kernel<<<SCAN_NBK, SCAN_TPB, 0, stream>>>(degp32, offsets, cdelta, state);
    {
        const int work = N_EDGES / 4;
        fill_kernel<<<(work + 255) / 256, 256, 0, stream>>>(ei, offsets, cdelta, rank, csr);
    }
    {
        const int waves  = (N_NODES + NPW - 1) / NPW;               // 6250
        const int blocks = (waves + (SBLK / 64) - 1) / (SBLK / 64); // 782
        sage_kernel<<<blocks, SBLK, 0, stream>>>(xb, offsets, csr, Wl, bl, Wr, out);
    }
}

// Round 11
// 127.015 us; speedup vs baseline: 1.4168x; 1.4168x over previous
//
#include <hip/hip_runtime.h>

#define N_NODES 100000
#define N_EDGES 1600000
#define D 64
#define NBKT 391                          // 256-node buckets: dst>>8
#define A_EPB 4096                        // edges per block in passes A1/A2
#define A_I4 (A_EPB / 4)                  // 1024 int4 per block
#define N_I4 (N_EDGES / 4)                // 400000
#define TB 20                             // max edges/thread in pass B (cap 5120/bucket)

typedef __attribute__((ext_vector_type(8))) short bf16x8;
typedef __attribute__((ext_vector_type(4))) float f32x4;

__device__ __forceinline__ unsigned short f2bf(float f) {
    union { float f; unsigned u; } v; v.f = f;
    unsigned r = v.u + 0x7FFFu + ((v.u >> 16) & 1u);
    return (unsigned short)(r >> 16);
}
__device__ __forceinline__ float bf2f_u(unsigned h) {   // low 16 bits -> float
    union { unsigned u; float f; } v; v.u = h << 16;
    return v.f;
}

// ---------------- pass A1: bucket counts (LDS-aggregated) + x->bf16 convert ----------------
#define CVT_BLKS 6250                     // 1.6M float4 / 256
__global__ __launch_bounds__(256) void bucket_count_cvt(const float* __restrict__ x,
                                                        unsigned short* __restrict__ xb,
                                                        const int* __restrict__ ei,
                                                        unsigned* __restrict__ bcnt) {
    __shared__ unsigned hc[NBKT];
    const int blk = blockIdx.x;
    const int tid = threadIdx.x;
    if (blk < NBKT) {
        for (int k = tid; k < NBKT; k += 256) hc[k] = 0;
        __syncthreads();
        const int g0 = blk * A_I4;
        const int4* dptr = (const int4*)(ei + N_EDGES);
        #pragma unroll
        for (int t = 0; t < 4; ++t) {
            const int g = g0 + tid + t * 256;
            if (g < N_I4) {
                int4 d4 = dptr[g];
                atomicAdd(&hc[d4.x >> 8], 1u);
                atomicAdd(&hc[d4.y >> 8], 1u);
                atomicAdd(&hc[d4.z >> 8], 1u);
                atomicAdd(&hc[d4.w >> 8], 1u);
            }
        }
        __syncthreads();
        for (int k = tid; k < NBKT; k += 256) {
            unsigned c = hc[k];
            if (c) atomicAdd(&bcnt[k], c);       // non-returning, fire-and-forget
        }
    } else {
        const int j = (blk - NBKT) * 256 + tid;  // float4 item
        if (j < CVT_BLKS * 256) {
            float4 v = ((const float4*)x)[j];
            ushort4 o;
            o.x = f2bf(v.x); o.y = f2bf(v.y); o.z = f2bf(v.z); o.w = f2bf(v.w);
            ((ushort4*)xb)[j] = o;
        }
    }
}

// ---------------- scan of 391 bucket totals (single block) ----------------
__global__ __launch_bounds__(512) void scanb_kernel(const unsigned* __restrict__ bcnt,
                                                    unsigned* __restrict__ bbase,
                                                    unsigned* __restrict__ bcursor) {
    __shared__ unsigned s[512];
    const int t = threadIdx.x;
    unsigned v = (t < NBKT) ? bcnt[t] : 0;
    s[t] = v;
    __syncthreads();
    for (int off = 1; off < 512; off <<= 1) {
        unsigned u = (t >= off) ? s[t - off] : 0;
        __syncthreads();
        s[t] += u;
        __syncthreads();
    }
    if (t < NBKT) {
        unsigned excl = s[t] - v;
        bbase[t]   = excl;
        bcursor[t] = excl;
        if (t == NBKT - 1) bbase[NBKT] = s[t];   // total = N_EDGES
    }
}

// ---------------- pass A2: scatter edges into bucket regions ----------------
__global__ __launch_bounds__(256) void bucket_scatter(const int* __restrict__ ei,
                                                      unsigned* __restrict__ bcursor,
                                                      unsigned* __restrict__ bpairs) {
    __shared__ unsigned hc[NBKT];
    __shared__ unsigned hb[NBKT];
    const int blk = blockIdx.x;
    const int tid = threadIdx.x;
    for (int k = tid; k < NBKT; k += 256) hc[k] = 0;
    __syncthreads();

    const int g0 = blk * A_I4;
    const int4* sptr = (const int4*)ei;
    const int4* dptr = (const int4*)(ei + N_EDGES);

    unsigned pay[16];    // (src<<8) | (dst & 255)
    unsigned meta[16];   // (bucket<<12) | lrank ; 0xFFFFFFFF = invalid
    #pragma unroll
    for (int t = 0; t < 4; ++t) {
        const int g = g0 + tid + t * 256;
        if (g < N_I4) {
            int4 s4 = sptr[g];
            int4 d4 = dptr[g];
            const int dd[4] = { d4.x, d4.y, d4.z, d4.w };
            const int ss[4] = { s4.x, s4.y, s4.z, s4.w };
            #pragma unroll
            for (int c = 0; c < 4; ++c) {
                const unsigned b = (unsigned)dd[c] >> 8;
                const unsigned lr = atomicAdd(&hc[b], 1u);
                meta[t * 4 + c] = (b << 12) | lr;
                pay[t * 4 + c]  = ((unsigned)ss[c] << 8) | ((unsigned)dd[c] & 255u);
            }
        } else {
            #pragma unroll
            for (int c = 0; c < 4; ++c) meta[t * 4 + c] = 0xFFFFFFFFu;
        }
    }
    __syncthreads();
    for (int k = tid; k < NBKT; k += 256) {
        unsigned c = hc[k];
        if (c) hb[k] = atomicAdd(&bcursor[k], c);
    }
    __syncthreads();
    #pragma unroll
    for (int e = 0; e < 16; ++e) {
        if (meta[e] != 0xFFFFFFFFu) {
            const unsigned b  = meta[e] >> 12;
            const unsigned lr = meta[e] & 0xFFFu;
            bpairs[hb[b] + lr] = pay[e];
        }
    }
}

// ---------------- pass B: per-bucket CSR build (in place) + offsets ----------------
__global__ __launch_bounds__(256) void bucket_csr(const unsigned* __restrict__ bbase,
                                                  unsigned* __restrict__ bpairs,
                                                  int* __restrict__ offsets) {
    __shared__ unsigned ncnt[256];
    __shared__ unsigned s[256];
    const int b   = blockIdx.x;
    const int tid = threadIdx.x;
    const unsigned base = bbase[b];
    const int cnt = (int)(bbase[b + 1] - base);

    ncnt[tid] = 0;
    __syncthreads();

    unsigned pk[TB];
    unsigned rk[TB];
    #pragma unroll
    for (int t = 0; t < TB; ++t) {
        const int i = tid + t * 256;
        if (i < cnt) {
            const unsigned p = bpairs[base + i];
            pk[t] = p;
            rk[t] = atomicAdd(&ncnt[p & 255u], 1u);
        } else {
            pk[t] = 0xFFFFFFFFu;
        }
    }
    __syncthreads();

    // 256-wide inclusive scan of ncnt
    const unsigned v = ncnt[tid];
    s[tid] = v;
    __syncthreads();
    for (int off = 1; off < 256; off <<= 1) {
        unsigned u = (tid >= off) ? s[tid - off] : 0;
        __syncthreads();
        s[tid] += u;
        __syncthreads();
    }
    const unsigned excl = s[tid] - v;
    ncnt[tid] = excl;                       // reuse as per-node local offset
    const int n0 = b * 256;
    if (n0 + tid < N_NODES) offsets[n0 + tid] = (int)(base + excl);
    if (b == NBKT - 1 && tid == 0) offsets[N_NODES] = N_EDGES;
    __syncthreads();

    #pragma unroll
    for (int t = 0; t < TB; ++t) {
        if (pk[t] != 0xFFFFFFFFu) {
            const unsigned p  = pk[t];
            const unsigned dl = p & 255u;
            bpairs[base + ncnt[dl] + rk[t]] = p >> 8;   // src
        }
    }
}

// 8 clamp-masked edge-pairs: lanes<32 take edge jj, lanes>=32 take edge jj+1,
// each lane holds 2 cols as a packed bf16 pair.
#define STEP8(SI, J, N, A0, A1)                                              \
    {                                                                         \
        _Pragma("unroll")                                                     \
        for (int t_ = 0; t_ < 8; ++t_) {                                      \
            const int jj_  = (J) + 2 * t_;                                    \
            const int jlo_ = (jj_     < (N)) ? jj_     : ((N) - 1);           \
            const int jhi_ = (jj_ + 1 < (N)) ? jj_ + 1 : ((N) - 1);           \
            const int slo_ = __builtin_amdgcn_readlane((SI), jlo_);           \
            const int shi_ = __builtin_amdgcn_readlane((SI), jhi_);           \
            const int sel_ = (lane >= 32) ? shi_ : slo_;                      \
            unsigned v_ = xb32[(size_t)sel_ * 32 + lc];                       \
            const bool ok_ = (lane < 32) ? (jj_ < (N)) : (jj_ + 1 < (N));     \
            v_ = ok_ ? v_ : 0u;                                               \
            (A0) += bf2f_u(v_ & 0xFFFFu);                                     \
            (A1) += bf2f_u(v_ >> 16);                                         \
        }                                                                     \
    }

// rare tail for degree > 64
#define TAILCH(S0, DD, A0, A1)                                               \
    for (int base_ = 64; base_ < (DD); base_ += 64) {                        \
        const int n2_ = ((DD) - base_ < 64) ? ((DD) - base_) : 64;           \
        const int cl2_ = (lane < n2_) ? lane : (n2_ - 1);                    \
        const int sit_ = csr[(S0) + base_ + cl2_];                           \
        for (int j_ = 0; j_ < n2_; j_ += 16) { STEP8(sit_, j_, n2_, A0, A1) }\
    }

// ---------------- fused gather + mean + MFMA matmul + bias + ReLU ----------------
#define NPW 16
#define SBLK 512
__global__ __launch_bounds__(SBLK) void sage_kernel(const unsigned short* __restrict__ xb,
                                                    const int* __restrict__ offsets,
                                                    const int* __restrict__ csr,
                                                    const float* __restrict__ Wl,
                                                    const float* __restrict__ bl,
                                                    const float* __restrict__ Wr,
                                                    float* __restrict__ out) {
    __shared__ unsigned short sWt[D * 2 * D];      // 64 cols x 128 k, 16 KB
    __shared__ float sbl[D];
    __shared__ unsigned int sA32[(SBLK / 64) * NPW * (2 * D / 2)];  // 8 waves x 16 rows x 64 uints

    const int tid = threadIdx.x;
    for (int i = tid; i < D * D; i += SBLK) {
        int k = i >> 6, c = i & 63;
        int swz = (c & 7) << 3;                     // ushort-index xor
        sWt[(c * 128 + k) ^ swz]      = f2bf(Wl[i]);
        sWt[(c * 128 + 64 + k) ^ swz] = f2bf(Wr[i]);
    }
    if (tid < D) sbl[tid] = bl[tid];
    __syncthreads();

    const int lane = tid & 63;
    const int wib  = tid >> 6;
    const int wid  = (blockIdx.x * (SBLK / 64)) + wib;
    const int node0 = wid * NPW;
    if (node0 >= N_NODES) return;

    const unsigned int* __restrict__ xb32 = (const unsigned int*)xb;
    unsigned int* sAw = sA32 + wib * (NPW * 64);
    const int lc = lane & 31;

    // ---- stage offsets for 17 boundaries with one lane-parallel load ----
    const int offl = offsets[node0 + ((lane <= NPW) ? lane : NPW)];

    // ---- stage csr chunk 0 for all 16 nodes (16 loads in flight) ----
    int si[NPW];
    int dg[NPW];
    #pragma unroll
    for (int r = 0; r < NPW; ++r) {
        const int s0 = __builtin_amdgcn_readlane(offl, r);
        const int s1 = __builtin_amdgcn_readlane(offl, r + 1);
        const int d  = s1 - s0;
        dg[r] = d;
        const int dm = (d > 0) ? d : 1;
        const int cl = (lane < dm) ? lane : (dm - 1);
        int addr = s0 + cl;
        addr = (addr < N_EDGES) ? addr : (N_EDGES - 1);
        si[r] = csr[addr];
    }

    // ---- gather: two nodes interleaved (16 xb loads in flight) ----
    #pragma unroll
    for (int p = 0; p < NPW / 2; ++p) {
        const int rA = 2 * p, rB = 2 * p + 1;
        const int dA = dg[rA], dB = dg[rB];
        const int nA = (dA < 64) ? dA : 64;
        const int nB = (dB < 64) ? dB : 64;

        const unsigned vselfA = xb32[(size_t)(node0 + rA) * 32 + lc];
        const unsigned vselfB = xb32[(size_t)(node0 + rB) * 32 + lc];

        float a0 = 0.0f, a1 = 0.0f, b0 = 0.0f, b1 = 0.0f;
        int jA = 0, jB = 0;
        while (jA < nA && jB < nB) {
            STEP8(si[rA], jA, nA, a0, a1)
            STEP8(si[rB], jB, nB, b0, b1)
            jA += 16; jB += 16;
        }
        while (jA < nA) { STEP8(si[rA], jA, nA, a0, a1) jA += 16; }
        while (jB < nB) { STEP8(si[rB], jB, nB, b0, b1) jB += 16; }
        if (dA > 64) {
            const int s0A = __builtin_amdgcn_readlane(offl, rA);
            TAILCH(s0A, dA, a0, a1)
        }
        if (dB > 64) {
            const int s0B = __builtin_amdgcn_readlane(offl, rB);
            TAILCH(s0B, dB, b0, b1)
        }

        a0 += __shfl_xor(a0, 32, 64);
        a1 += __shfl_xor(a1, 32, 64);
        b0 += __shfl_xor(b0, 32, 64);
        b1 += __shfl_xor(b1, 32, 64);
        const float invA = 1.0f / fmaxf((float)dA, 1.0f);
        const float invB = 1.0f / fmaxf((float)dB, 1.0f);
        const unsigned mpA = ((unsigned)f2bf(a1 * invA) << 16) | f2bf(a0 * invA);
        const unsigned mpB = ((unsigned)f2bf(b1 * invB) << 16) | f2bf(b0 * invB);
        const int swzA = (rA & 7) << 2;
        const int swzB = (rB & 7) << 2;
        if (lane < 32) {
            sAw[(rA * 64 + lc) ^ swzA] = mpA;
            sAw[(rB * 64 + lc) ^ swzB] = mpB;
        } else {
            sAw[(rA * 64 + 32 + lc) ^ swzA] = vselfA;
            sAw[(rB * 64 + 32 + lc) ^ swzB] = vselfB;
        }
    }

    // ---- MFMA phase ----
    const unsigned short* sAu = (const unsigned short*)sAw;
    const int row = lane & 15;
    const int kb  = lane >> 4;

    bf16x8 afr[4];
    #pragma unroll
    for (int kc = 0; kc < 4; ++kc) {
        int us = (row * 128 + kc * 32 + kb * 8) ^ ((row & 7) << 3);
        afr[kc] = *(const bf16x8*)(sAu + us);
    }

    #pragma unroll
    for (int ct = 0; ct < 4; ++ct) {
        const int col = ct * 16 + row;
        f32x4 acc = {0.0f, 0.0f, 0.0f, 0.0f};
        #pragma unroll
        for (int kc = 0; kc < 4; ++kc) {
            int us = (col * 128 + kc * 32 + kb * 8) ^ ((col & 7) << 3);
            bf16x8 bfr = *(const bf16x8*)(sWt + us);
            acc = __builtin_amdgcn_mfma_f32_16x16x32_bf16(afr[kc], bfr, acc, 0, 0, 0);
        }
        const float bias = sbl[col];
        const int crow0 = (lane >> 4) * 4;
        #pragma unroll
        for (int i = 0; i < 4; ++i) {
            out[(node0 + crow0 + i) * D + col] = fmaxf(acc[i] + bias, 0.0f);
        }
    }
}

// ---------------- launch ----------------
extern "C" void kernel_launch(void* const* d_in, const int* in_sizes, int n_in,
                              void* d_out, int out_size, void* d_ws, size_t ws_size,
                              hipStream_t stream) {
    const float* x  = (const float*)d_in[0];
    const int*   ei = (const int*)d_in[1];    // [2, N_EDGES] flat: src then dst
    const float* Wl = (const float*)d_in[2];
    const float* bl = (const float*)d_in[3];
    const float* Wr = (const float*)d_in[4];
    float* out = (float*)d_out;

    // workspace layout (~19.6 MB), 16B-aligned segments
    unsigned* bcnt    = (unsigned*)d_ws;                 // 391 -> pad 512
    unsigned* bbase   = bcnt + 512;                      // 392 -> pad 512
    unsigned* bcursor = bbase + 512;                     // 391 -> pad 512
    int* offsets      = (int*)(bcursor + 512);           // N_NODES+1 -> pad 100004
    unsigned* bpairs  = (unsigned*)(offsets + 100004);   // N_EDGES (becomes csr in place)
    unsigned short* xb = (unsigned short*)(bpairs + N_EDGES);  // N_NODES * D

    hipMemsetAsync(bcnt, 0, 512 * sizeof(unsigned), stream);

    bucket_count_cvt<<<NBKT + CVT_BLKS, 256, 0, stream>>>(x, xb, ei, bcnt);
    scanb_kernel<<<1, 512, 0, stream>>>(bcnt, bbase, bcursor);
    bucket_scatter<<<NBKT, 256, 0, stream>>>(ei, bcursor, bpairs);
    bucket_csr<<<NBKT, 256, 0, stream>>>(bbase, bpairs, offsets);

    {
        const int waves  = (N_NODES + NPW - 1) / NPW;               // 6250
        const int blocks = (waves + (SBLK / 64) - 1) / (SBLK / 64); // 782
        sage_kernel<<<blocks, SBLK, 0, stream>>>(xb, offsets, (const int*)bpairs,
                                                 Wl, bl, Wr, out);
    }
}